// Round 12
// baseline (26394.763 us; speedup 1.0000x reference)
//
#include <hip/hip_runtime.h>
#include <math.h>

#define A_ 64
#define B_ 256
#define D_ 128
#define H_ 512
#define STOT 16384
#define NWG 32

// s_getreg immediate: id | offset<<6 | (width-1)<<11 ; HW_REG_XCC_ID = 20
#define XCC_GETREG_IMM (20 | (31 << 11))

// workspace layout (float offsets)
#define OFF_XT    0
#define N_XT      (A_*D_*B_)              // transposed input [t][k][b]
#define OFF_HT0   (OFF_XT + N_XT)         // encoder h ping  [j][b]
#define OFF_HT1   (OFF_HT0 + H_*B_)       // encoder h pong
#define OFF_CT    (OFF_HT1 + H_*B_)       // encoder c       [j][b]
#define OFF_HTAP  (OFF_CT + H_*B_)        // decoder h taps  [256][512]
#define OFF_HB    (OFF_HTAP + B_*H_)      // decoder h double buffer [2][512] f32
#define OFF_FLG   (OFF_HB + 2*H_)         // 32 step-flags (monotonic)
#define OFF_CINIT (OFF_FLG + 32)          // decoder initial c [512]
#define OFF_ELECT (OFF_CINIT + H_)        // ints: [0..7] per-XCD counters, [8] winner

__device__ __forceinline__ float sigf(float x) {
  return __builtin_amdgcn_rcpf(1.0f + __expf(-x));
}
// tanh(x) = 1 - 2/(e^{2x}+1); exact at saturation
__device__ __forceinline__ float tanhfast(float x) {
  return 1.0f - 2.0f * __builtin_amdgcn_rcpf(__expf(2.0f * x) + 1.0f);
}

// nt load: no L1 allocation => never a stale-L1 hit; served by the XCD-shared
// L2 (all participants elected onto one XCD). "=&v" early-clobber mandatory.
__device__ __forceinline__ unsigned load_nt32(const unsigned* p) {
  unsigned v;
  asm volatile("global_load_dword %0, %1, off nt\n\ts_waitcnt vmcnt(0)"
               : "=&v"(v) : "v"(p) : "memory");
  return v;
}
// liveness fallback (round-5-proven): L1 invalidate + load. Used 1/64 spins.
__device__ __forceinline__ unsigned load_inv32(const unsigned* p) {
  unsigned v;
  asm volatile("buffer_inv sc0\n\t"
               "global_load_dword %0, %1, off nt\n\ts_waitcnt vmcnt(0)"
               : "=&v"(v) : "v"(p) : "memory");
  return v;
}
// nt store: write-through leaving a CLEAN L2 copy that nt polls hit without
// evict/writeback storms (round 8/10 lessons: dirty or scattered handshake
// lines ping-pong through HBM). Data = ONE 64B coalesced store per WG.
__device__ __forceinline__ void store_nt32(unsigned* p, unsigned v) {
  asm volatile("global_store_dword %0, %1, off nt" :: "v"(p), "v"(v) : "memory");
}

// ---------------------------------------------------------------------------
// init1: transpose input to XT[t][k][b], zero encoder h0/c0
// ---------------------------------------------------------------------------
__global__ void init1(const float* __restrict__ in0, float* __restrict__ ws) {
  float* XT  = ws + OFF_XT;
  float* HT0 = ws + OFF_HT0;
  float* CT  = ws + OFF_CT;
  int stride = gridDim.x * blockDim.x;
  for (int idx = blockIdx.x * blockDim.x + threadIdx.x; idx < N_XT; idx += stride) {
    int t = idx >> 15;
    int k = (idx >> 8) & 127;
    int b = idx & 255;
    XT[idx] = in0[t * (B_ * D_) + b * D_ + k];
    if (idx < H_ * B_) { HT0[idx] = 0.f; CT[idx] = 0.f; }
  }
}

// ---------------------------------------------------------------------------
// enc_step: one encoder LSTM timestep, fused GEMM (256x2048x640) + update.
// ---------------------------------------------------------------------------
__global__ __launch_bounds__(256) void enc_step(
    const float* __restrict__ XT, const float* __restrict__ Wih,
    const float* __restrict__ Whh, const float* __restrict__ bih,
    const float* __restrict__ bhh, const float* __restrict__ Hin,
    float* __restrict__ Hout, float* __restrict__ C, int t) {
  __shared__ float Wt[16 * 68];
  __shared__ float XHt[16 * 32];
  __shared__ float gs[64 * 33];
  const int tid = threadIdx.x;
  const int jt = blockIdx.x;
  const int bt = blockIdx.y;
  const int rr = tid >> 4;
  const int bb = tid & 15;

  float acc[4][2];
#pragma unroll
  for (int i = 0; i < 4; ++i) {
    int r = 4 * rr + i;
    int Row = ((r >> 4) << 9) + (jt << 4) + (r & 15);
    float bv = bih[Row] + bhh[Row];
    acc[i][0] = bv; acc[i][1] = bv;
  }

  for (int kt = 0; kt < 40; ++kt) {
    int k0 = kt << 4;
    __syncthreads();
#pragma unroll
    for (int e = 0; e < 4; ++e) {
      int idx = tid + (e << 8);
      int kk = idx & 15, r = idx >> 4;
      int Row = ((r >> 4) << 9) + (jt << 4) + (r & 15);
      int k = k0 + kk;
      float v = (k < D_) ? Wih[Row * D_ + k] : Whh[Row * H_ + (k - D_)];
      Wt[kk * 68 + r] = v;
    }
#pragma unroll
    for (int e = 0; e < 2; ++e) {
      int idx = tid + (e << 8);
      int kk = idx >> 5, b = idx & 31;
      int k = k0 + kk;
      int gb = (bt << 5) + b;
      float v = (k < D_) ? XT[(t * D_ + k) * B_ + gb] : Hin[(k - D_) * B_ + gb];
      XHt[kk * 32 + b] = v;
    }
    __syncthreads();
#pragma unroll
    for (int kk = 0; kk < 16; ++kk) {
      const float4 wv = *(const float4*)&Wt[kk * 68 + 4 * rr];
      const float2 xv = *(const float2*)&XHt[kk * 32 + 2 * bb];
      acc[0][0] += wv.x * xv.x; acc[0][1] += wv.x * xv.y;
      acc[1][0] += wv.y * xv.x; acc[1][1] += wv.y * xv.y;
      acc[2][0] += wv.z * xv.x; acc[2][1] += wv.z * xv.y;
      acc[3][0] += wv.w * xv.x; acc[3][1] += wv.w * xv.y;
    }
  }
  __syncthreads();
#pragma unroll
  for (int i = 0; i < 4; ++i) {
    gs[(4 * rr + i) * 33 + 2 * bb]     = acc[i][0];
    gs[(4 * rr + i) * 33 + 2 * bb + 1] = acc[i][1];
  }
  __syncthreads();
#pragma unroll
  for (int e = 0; e < 2; ++e) {
    int idx = tid + (e << 8);
    int jj = idx >> 5, b = idx & 31;
    int gb = (bt << 5) + b;
    float iv = gs[jj * 33 + b];
    float fv = gs[(16 + jj) * 33 + b];
    float gv = gs[(32 + jj) * 33 + b];
    float ov = gs[(48 + jj) * 33 + b];
    int addr = ((jt << 4) + jj) * B_ + gb;
    float c = C[addr];
    c = sigf(fv) * c + sigf(iv) * tanhf(gv);
    C[addr] = c;
    Hout[addr] = sigf(ov) * tanhf(c);
  }
}

// ---------------------------------------------------------------------------
// init2: seed h double buffer (h0 in parity 1), zero flags, seed c, HTAP[0],
// reset election.
// ---------------------------------------------------------------------------
__global__ void init2(float* __restrict__ ws) {
  const float* Hfin = ws + OFF_HT0;   // after 64 steps final h lands in HT0
  const float* CT   = ws + OFF_CT;
  float* HB   = ws + OFF_HB;
  unsigned* FLG = (unsigned*)(ws + OFF_FLG);
  float* CIN  = ws + OFF_CINIT;
  float* HTAP = ws + OFF_HTAP;
  int* EL     = (int*)(ws + OFF_ELECT);
  int j = threadIdx.x;                // 512 threads
  float hj = Hfin[j * B_ + 255];
  HB[H_ + j] = hj;                    // h_0 lives in parity 1
  HB[j]      = 0.f;
  CIN[j]  = CT[j * B_ + 255];
  HTAP[j] = hj;
  if (j < 32) FLG[j] = 0;             // flags[w] = steps completed by WG w
  if (j < 8) EL[j] = 0;
  if (j == 8) EL[8] = -1;             // winner xcd
}

// ---------------------------------------------------------------------------
// decoder (scalar-flag protocol): 256 WGs launched; the 32 on one elected
// XCD run 16384 lock-step steps; others exit.
// Per step: wave0 polls the 32 flags (ONE coalesced 128B nt load + __all,
// ~6 instr/spin — replaces R6's 16 waves x 32 tagged-u64 polls that burned
// ~44% of active-CU VALU issue) -> LDS flag wakes siblings -> each wave
// loads its 32-float h slice ONCE (coalesced nt) -> stages to LDS -> K-split
// partials -> barrier -> wave15 reduces, updates c, publishes 16 h floats
// as ONE 64B nt store, vmcnt(0), then the 4B flag store (same-L2 ordering:
// flag implies data). Flags are monotonic step counts: flags[i] >= s proves
// WG_i consumed h_{s-1}, so the 2-step parity overwrite is safe (same
// induction as rounds 2-11).
// ---------------------------------------------------------------------------
__global__ __launch_bounds__(1024) void decoder(
    const float* __restrict__ in0, const float* __restrict__ Wih,
    const float* __restrict__ Whh, const float* __restrict__ bih,
    const float* __restrict__ bhh, float* __restrict__ ws) {
  float* HB = ws + OFF_HB;
  unsigned* FLG = (unsigned*)(ws + OFF_FLG);
  float* HTAP = ws + OFF_HTAP;
  const float* CIN = ws + OFF_CINIT;

  __shared__ float part[2][16 * 64];  // [parity][wave][row]
  __shared__ float hstage[H_];        // wave-private 32-float chunks
  __shared__ int lflag;               // monotonic step relay
  __shared__ int role;

  const int tid = threadIdx.x;

  // ---- election: first XCD to seat 32 WGs wins; its ranks 0..31 decode ----
  if (tid == 0) {
    unsigned xcc = ((unsigned)__builtin_amdgcn_s_getreg(XCC_GETREG_IMM)) & 7u;
    int* EL = (int*)(ws + OFF_ELECT);
    int r = __hip_atomic_fetch_add(&EL[xcc], 1, __ATOMIC_RELAXED,
                                   __HIP_MEMORY_SCOPE_AGENT);
    int myrole = -1;
    if (r < NWG) {
      if (r == NWG - 1) {
        int exp = -1;
        __hip_atomic_compare_exchange_strong(&EL[8], &exp, (int)xcc,
            __ATOMIC_RELAXED, __ATOMIC_RELAXED, __HIP_MEMORY_SCOPE_AGENT);
      }
      int wx;
      do {
        wx = __hip_atomic_load(&EL[8], __ATOMIC_RELAXED, __HIP_MEMORY_SCOPE_AGENT);
        if (wx == -1) __builtin_amdgcn_s_sleep(2);
      } while (wx == -1);
      if (wx == (int)xcc) myrole = r;
    }
    role = myrole;
    lflag = -1;
  }
  __syncthreads();
  if (role < 0) return;               // uniform per WG
  const int w = role;

  const int v = tid >> 6;             // wave -> k-chunk [32v, 32v+32)
  const int l = tid & 63;             // lane -> local gate row
  const int R = ((l >> 4) << 9) + (w << 4) + (l & 15);  // global gate row

  float4 wa[8];
#pragma unroll
  for (int k = 0; k < 8; ++k)
    wa[k] = *(const float4*)&Whh[R * H_ + (v << 5) + 4 * k];
  float4 wx0 = *(const float4*)&Wih[R * D_ + (v << 3)];
  float4 wx1 = *(const float4*)&Wih[R * D_ + (v << 3) + 4];

  float bias = 0.f, c = 0.f;
  if (v == 15) {                      // tail wave holds bias (per row) and c
    bias = bih[R] + bhh[R];
    if (l < 16) c = CIN[(w << 4) + l];
  }

  const int pe = (v << 5) + (l & 31); // staged element (2 lanes per element)

  for (int s = 0; s < STOT; ++s) {
    const int p = (s + 1) & 1;        // read parity for h_s
    // x loads — independent of h, issued before the wait to overlap
    const int tt = s & 63;
    const int bc = 255 - (s >> 6);
    const float* xp = in0 + (tt * B_ + bc) * D_ + (v << 3);
    float4 x0 = *(const float4*)xp;
    float4 x1 = *(const float4*)(xp + 4);

    if (v == 0) {
      // ---- global detect: all 32 flags >= s (coalesced 128B nt load) ----
      const unsigned* fp = FLG + (l & 31);
      int spins = 0;
      for (;;) {
        unsigned f = ((++spins & 63) == 0) ? load_inv32(fp) : load_nt32(fp);
        if (__all((int)f >= s)) break;
      }
      if (l == 0) *(volatile int*)&lflag = s;
    } else {
      while (*(volatile int*)&lflag < s) { }
      __asm__ volatile("" ::: "memory");   // no hoisting of h loads
    }

    // ---- load own h slice ONCE (clean L2 lines), stage to LDS ----------
    if (l < 32)
      hstage[pe] = __uint_as_float(load_nt32((const unsigned*)&HB[(p << 9) + pe]));
    // intra-wave LDS dependency: compiler's lgkmcnt wait suffices.

    float pacc = wx0.x * x0.x + wx0.y * x0.y + wx0.z * x0.z + wx0.w * x0.w
               + wx1.x * x1.x + wx1.y * x1.y + wx1.z * x1.z + wx1.w * x1.w;

    const float4* hp = (const float4*)&hstage[v << 5];
#pragma unroll
    for (int k = 0; k < 8; ++k) {
      float4 h4 = hp[k];                  // wave-uniform address: LDS broadcast
      pacc += wa[k].x * h4.x + wa[k].y * h4.y + wa[k].z * h4.z + wa[k].w * h4.w;
    }
    part[s & 1][(v << 6) + l] = pacc;
    __syncthreads();                      // the ONE barrier per step

    if (v == 15) {                        // tail: reduce + update + publish
      float g = bias;
#pragma unroll
      for (int j = 0; j < 16; ++j) g += part[s & 1][(j << 6) + l];
      const int e = l & 15;
      float vi = __shfl(g, e);
      float vf = __shfl(g, e + 16);
      float vg = __shfl(g, e + 32);
      float vo = __shfl(g, e + 48);
      if (l < 16) {
        c = sigf(vf) * c + sigf(vi) * tanhfast(vg);
        float hn = sigf(vo) * tanhfast(c);
        if ((s & 63) == 63) {
          int q = (s >> 6) + 1;
          if (q < 256) HTAP[q * H_ + (w << 4) + l] = hn;
        }
        // ONE coalesced 64B nt store (16 contiguous floats), then drain,
        // then the flag — same-L2 ordering makes flag imply data.
        store_nt32((unsigned*)&HB[((s & 1) << 9) + (w << 4) + l],
                   __float_as_uint(hn));
        asm volatile("s_waitcnt vmcnt(0)" ::: "memory");
      }
      if (l == 0) store_nt32(&FLG[w], (unsigned)(s + 1));
    }
  }
}

// ---------------------------------------------------------------------------
// out_proj: outs[255-b] = Htap[255-b] @ lin_W^T + lin_b, broadcast over a.
// ---------------------------------------------------------------------------
__global__ __launch_bounds__(128) void out_proj(
    const float* __restrict__ ws, const float* __restrict__ linW,
    const float* __restrict__ linb, float* __restrict__ out) {
  const float* HTAP = ws + OFF_HTAP;
  __shared__ float hs[H_];
  const int b = blockIdx.x;
  const int i = 255 - b;
  const int d = threadIdx.x;
  *(float4*)&hs[4 * d] = *(const float4*)&HTAP[i * H_ + 4 * d];
  __syncthreads();
  float acc = linb[d];
#pragma unroll 8
  for (int k = 0; k < H_; k += 4) {
    float4 w4 = *(const float4*)&linW[d * H_ + k];
    acc += w4.x * hs[k] + w4.y * hs[k + 1] + w4.z * hs[k + 2] + w4.w * hs[k + 3];
  }
  for (int a = 0; a < A_; ++a)
    out[(a * B_ + b) * D_ + d] = acc;
}

// ---------------------------------------------------------------------------
extern "C" void kernel_launch(void* const* d_in, const int* in_sizes, int n_in,
                              void* d_out, int out_size, void* d_ws, size_t ws_size,
                              hipStream_t stream) {
  const float* in0  = (const float*)d_in[0];
  const float* eWih = (const float*)d_in[1];
  const float* eWhh = (const float*)d_in[2];
  const float* ebih = (const float*)d_in[3];
  const float* ebhh = (const float*)d_in[4];
  const float* dWih = (const float*)d_in[5];
  const float* dWhh = (const float*)d_in[6];
  const float* dbih = (const float*)d_in[7];
  const float* dbhh = (const float*)d_in[8];
  const float* linW = (const float*)d_in[9];
  const float* linb = (const float*)d_in[10];
  float* ws = (float*)d_ws;
  float* out = (float*)d_out;

  init1<<<2048, 256, 0, stream>>>(in0, ws);

  const float* XT = ws + OFF_XT;
  for (int t = 0; t < 64; ++t) {
    float* Hin  = ws + ((t & 1) ? OFF_HT1 : OFF_HT0);
    float* Hout = ws + ((t & 1) ? OFF_HT0 : OFF_HT1);
    enc_step<<<dim3(32, 8), 256, 0, stream>>>(XT, eWih, eWhh, ebih, ebhh,
                                              Hin, Hout, ws + OFF_CT, t);
  }
  init2<<<1, 512, 0, stream>>>(ws);
  decoder<<<256, 1024, 0, stream>>>(in0, dWih, dWhh, dbih, dbhh, ws);
  out_proj<<<256, 128, 0, stream>>>(ws, linW, linb, out);
}